// Round 1
// 155.425 us; speedup vs baseline: 1.0018x; 1.0018x over previous
//
#include <hip/hip_runtime.h>
#include <hip/hip_bf16.h>

// Locally-connected conv, ALL FP32 in/out, bf16 MFMA compute.
//   x:   (32, 16, 64, 64)        float
//   w:   (60, 60, 16, 5, 5, 16)  float   (per-position 400x16, k innermost)
//   out: (32, 16, 60, 60)        float
//
// Round-7: kill the per-position DMA->barrier serialization.
//  * ONE WAVE per output position (M=32,N=16,K=400 is just 2 MFMA tiles x
//    13 K-steps = 26 MFMAs). No K-split, no sRed reduce, no W LDS tile.
//  * W B-fragments loaded straight to registers: 8 dword loads/lane/step;
//    lanes 0-15 are contiguous 64B, qh-pairs merge to 128B segments ->
//    fully coalesced, each W byte read exactly once (92.2 MB stream).
//  * No barrier in the main loop; 900 blocks (4 pos each) all co-resident
//    (LDS 8 KB, __launch_bounds__(256,4)) -> deep TLP hides HBM latency,
//    kernel becomes W-BW-bound (~15 us floor).
//  * transpose_out kernel FUSED AWAY: 4 waves = 4 consecutive positions,
//    8 KB LDS transpose, float4 stores straight to out. Saves the 14.7 MB
//    ws round-trip + one launch. Chunked bijective XCD swizzle keeps
//    consecutive positions on one XCD so 16B out-stores merge in L2.

#define OUT_HW 60
#define IN_HW  64
#define CIN    16
#define COUT   16
#define NPOS   3600              // OUT_HW*OUT_HW
#define XC_ELE (32u * 64u * 64u * 16u)   // 2,097,152 bf16 elements

typedef __attribute__((ext_vector_type(8))) short bf16x8;
typedef __attribute__((ext_vector_type(4))) float f32x4;

static __device__ __forceinline__ unsigned pk2(float a, float b) {
    union { __hip_bfloat162 h; unsigned u; } cv;
    cv.h = __float22bfloat162_rn(make_float2(a, b));
    return cv.u;
}

// ---- prepass: xc[b][h][w][c] bf16 <- x[b][c][h][w] fp32 (proven r5/r6) ----
__global__ __launch_bounds__(256)
void make_xc(const float* __restrict__ x, ushort* __restrict__ xc) {
    const int bh = blockIdx.x;               // b*64 + h
    const int b = bh >> 6, h = bh & 63;
    const int t = threadIdx.x;
    const int cq = t & 3, wc = t >> 2;
    const float* src = x + ((size_t)(b * CIN) * IN_HW + h) * IN_HW + wc;
    float f[4];
#pragma unroll
    for (int e = 0; e < 4; ++e)
        f[e] = src[(size_t)(cq * 4 + e) * (IN_HW * IN_HW)];
    union { ushort4 v; unsigned u[2]; } o;
    o.u[0] = pk2(f[0], f[1]);
    o.u[1] = pk2(f[2], f[3]);
    *(ushort4*)&xc[((size_t)bh * IN_HW + wc) * CIN + cq * 4] = o.v;
}

// ---- main: 900 blocks x 256 thr; wave wv owns position wg*4+wv ----
__global__ __launch_bounds__(256, 4)
void lc_wave(const ushort* __restrict__ xc, const float* __restrict__ w,
             float* __restrict__ out) {
    __shared__ float sOut[4][512];           // 8 KB: 4 positions x (b*16+k)

    // bijective chunked XCD swizzle (m204 recipe): 900 = 8*112 + 4
    const int bid = blockIdx.x;              // 0..899
    const int xcd = bid & 7, ii = bid >> 3;
    const int wg = (xcd < 4 ? xcd * 113 : 452 + (xcd - 4) * 112) + ii;

    const int t = threadIdx.x;
    const int lane = t & 63, wv = t >> 6;
    const int pos = wg * 4 + wv;             // this wave's output position
    const int i = pos / OUT_HW, j = pos - i * OUT_HW;
    const int l15 = lane & 15, q = lane >> 4;
    const int qh = q >> 1;                   // uv parity within K-step
    const int ch = (q & 1) << 3;             // c half: 0 or 8

    // per-lane W base: w[pos][c=ch][uv=qh][k=l15]; step offsets are
    // jj*1600B (c) + cc*128B (uv pair) -> compile-time after unroll.
    const float* wp = w + (size_t)pos * 6400 + (ch * 25 + qh) * 16 + l15;

    const int base_hw = i * IN_HW + j;
    const ushort* xb = xc + (size_t)l15 * (IN_HW * IN_HW * CIN) + ch; // b=l15

    f32x4 acc0 = {0.f, 0.f, 0.f, 0.f}, acc1 = {0.f, 0.f, 0.f, 0.f};
#pragma unroll
    for (int cc = 0; cc < 13; ++cc) {
        const int uv = cc * 2 + qh;          // reduction uv for this lane
        const int ok = (uv < 25);            // only cc==12, qh==1 fails
        const int uvc = ok ? uv : 24;        // clamped; B=0 there
        const int u = (uvc * 13) >> 6;       // uv/5 for uv<=24
        const int v = uvc - 5 * u;

        // A-fragments: 16B vector loads from xc (L2-resident, 4 MB)
        const ushort* xp = xb + (size_t)(base_hw + u * IN_HW + v) * CIN;
        bf16x8 a0 = *(const bf16x8*)xp;                                  // b = l15
        bf16x8 a1 = *(const bf16x8*)(xp + 16u * IN_HW * IN_HW * CIN);    // b + 16

        // B-fragment: 8 coalesced dword loads of W, cvt to bf16 in-reg
        float bw[8];
#pragma unroll
        for (int jj = 0; jj < 8; ++jj)
            bw[jj] = ok ? wp[jj * 400 + cc * 32] : 0.f;
        union { bf16x8 v; unsigned u[4]; } pb;
#pragma unroll
        for (int jj = 0; jj < 4; ++jj)
            pb.u[jj] = pk2(bw[2 * jj], bw[2 * jj + 1]);

        acc0 = __builtin_amdgcn_mfma_f32_16x16x32_bf16(a0, pb.v, acc0, 0, 0, 0);
        acc1 = __builtin_amdgcn_mfma_f32_16x16x32_bf16(a1, pb.v, acc1, 0, 0, 0);
    }

    // ---- epilogue: per-wave D tile -> LDS, then float4 stores to out ----
    // D layout (16x16x32 bf16): col = lane&15 (=k), row = q*4 + reg (=b)
#pragma unroll
    for (int r = 0; r < 4; ++r) {
        sOut[wv][(q * 4 + r) * 16 + l15]      = acc0[r];   // b = q*4+r
        sOut[wv][(q * 4 + r + 16) * 16 + l15] = acc1[r];   // b + 16
    }
    __syncthreads();
    const int p0 = wg * 4;
#pragma unroll
    for (int h = 0; h < 2; ++h) {
        const int o = t + h * 256;                         // o = b*16 + k
        f32x4 vo = { sOut[0][o], sOut[1][o], sOut[2][o], sOut[3][o] };
        *(f32x4*)(out + (size_t)o * NPOS + p0) = vo;       // 16B aligned
    }
}

// ---- emergency fallback (ws too small): naive, correct, slow ----
__global__ __launch_bounds__(256)
void lc_naive(const float* __restrict__ x, const float* __restrict__ w,
              float* __restrict__ out) {
    const int gid = blockIdx.x * 256 + threadIdx.x;
    if (gid >= 32 * COUT * NPOS) return;
    const int j = gid % OUT_HW;
    int rest = gid / OUT_HW;
    const int i = rest % OUT_HW; rest /= OUT_HW;
    const int k = rest % COUT;
    const int b = rest / COUT;
    const float* wp = w + (size_t)(i * OUT_HW + j) * 6400 + k;
    float s = 0.f;
    for (int c = 0; c < CIN; ++c)
        for (int u = 0; u < 5; ++u)
            for (int v = 0; v < 5; ++v)
                s += x[((size_t)(b * CIN + c) * IN_HW + i + u) * IN_HW + j + v]
                   * wp[((c * 5 + u) * 5 + v) * COUT];
    out[gid] = s;
}

extern "C" void kernel_launch(void* const* d_in, const int* in_sizes, int n_in,
                              void* d_out, int out_size, void* d_ws, size_t ws_size,
                              hipStream_t stream) {
    const float* x = (const float*)d_in[0];
    const float* w = (const float*)d_in[1];
    float* out = (float*)d_out;

    const size_t xcBytes = (size_t)XC_ELE * 2;   // 4,194,304

    if (ws_size >= xcBytes) {
        ushort* xc = (ushort*)d_ws;
        make_xc<<<32 * IN_HW, 256, 0, stream>>>(x, xc);
        lc_wave<<<900, 256, 0, stream>>>(xc, w, out);
    } else {
        lc_naive<<<(32 * COUT * NPOS + 255) / 256, 256, 0, stream>>>(x, w, out);
    }
}

// Round 2
// 155.078 us; speedup vs baseline: 1.0041x; 1.0022x over previous
//
#include <hip/hip_runtime.h>
#include <hip/hip_bf16.h>

// Locally-connected conv, ALL FP32 in/out, bf16 MFMA compute.
//   x:   (32, 16, 64, 64)        float
//   w:   (60, 60, 16, 5, 5, 16)  float   (per-position 400x16, k innermost)
//   out: (32, 16, 60, 60)        float
//
// Round-8: attack lc_wave's latency-bound regime (3.5 waves/SIMD is too few
// to hide ~900cy HBM latency on the W stream; Little's law shortfall).
//  * 2-way K-SPLIT: block = 2 positions x 2 K-halves (7+6 of 13 steps).
//    Grid 900 -> 1800 blocks, 14 -> 28 waves/CU (7/SIMD): 2x the in-flight
//    W loads per CU. Cross-half reduce via 8 KB LDS + float2 stores.
//  * Masked step peeled: only wave-half 1's last step (uv=25) carries the
//    cndmask/select chain; the other 12 steps are branch-free.
//  * 1800 = 8*225: perfectly bijective chunked XCD swizzle; the 16 blocks
//    sharing each 128B out-line are consecutive wg on one XCD -> L2 merge.
//  * Everything else proven in r7: xc bf16 prepass, A-frags via 16B loads,
//    W straight to registers (each byte read once, 2x128B per instr).

#define OUT_HW 60
#define IN_HW  64
#define CIN    16
#define COUT   16
#define NPOS   3600              // OUT_HW*OUT_HW
#define XC_ELE (32u * 64u * 64u * 16u)   // 2,097,152 bf16 elements

typedef __attribute__((ext_vector_type(8))) short bf16x8;
typedef __attribute__((ext_vector_type(4))) float f32x4;

static __device__ __forceinline__ unsigned pk2(float a, float b) {
    union { __hip_bfloat162 h; unsigned u; } cv;
    cv.h = __float22bfloat162_rn(make_float2(a, b));
    return cv.u;
}

// ---- prepass: xc[b][h][w][c] bf16 <- x[b][c][h][w] fp32 (proven r5-r7) ----
__global__ __launch_bounds__(256)
void make_xc(const float* __restrict__ x, ushort* __restrict__ xc) {
    const int bh = blockIdx.x;               // b*64 + h
    const int b = bh >> 6, h = bh & 63;
    const int t = threadIdx.x;
    const int cq = t & 3, wc = t >> 2;
    const float* src = x + ((size_t)(b * CIN) * IN_HW + h) * IN_HW + wc;
    float f[4];
#pragma unroll
    for (int e = 0; e < 4; ++e)
        f[e] = src[(size_t)(cq * 4 + e) * (IN_HW * IN_HW)];
    union { ushort4 v; unsigned u[2]; } o;
    o.u[0] = pk2(f[0], f[1]);
    o.u[1] = pk2(f[2], f[3]);
    *(ushort4*)&xc[((size_t)bh * IN_HW + wc) * CIN + cq * 4] = o.v;
}

// ---- main: 1800 blocks x 256 thr; wave (pw,kh) = pos wg*2+pw, K-half kh ----
__global__ __launch_bounds__(256, 6)
void lc_wave(const ushort* __restrict__ xc, const float* __restrict__ w,
             float* __restrict__ out) {
    __shared__ float sOut[4][512];           // 8 KB: per-wave partial D tiles

    // bijective chunked XCD swizzle: 1800 = 8 * 225
    const int bid = blockIdx.x;              // 0..1799
    const int wg = (bid & 7) * 225 + (bid >> 3);

    const int t = threadIdx.x;
    const int lane = t & 63, wv = t >> 6;
    const int pw = wv & 1, kh = wv >> 1;     // position-within-block, K-half
    const int pos = wg * 2 + pw;
    const int i = pos / OUT_HW, j = pos - i * OUT_HW;
    const int l15 = lane & 15, q = lane >> 4;
    const int qh = q >> 1;                   // uv parity within K-step
    const int ch = (q & 1) << 3;             // c half: 0 or 8

    // per-lane W base: w[pos][c=ch][uv=qh][k=l15]
    const float* wp = w + (size_t)pos * 6400 + (ch * 25 + qh) * 16 + l15;

    const int base_hw = i * IN_HW + j;
    const ushort* xb = xc + (size_t)l15 * (IN_HW * IN_HW * CIN) + ch; // b=l15

    f32x4 acc0 = {0.f, 0.f, 0.f, 0.f}, acc1 = {0.f, 0.f, 0.f, 0.f};

    // one K-step: reduction chunk cc covers uv = {2cc, 2cc+1} x c = 0..15
    auto step = [&](int cc, bool maskTail) {
        const int uv = cc * 2 + qh;
        const bool ok = !maskTail || (uv < 25);  // folds away when !maskTail
        const int uvc = ok ? uv : 24;            // clamped; B=0 there
        const int u = (uvc * 13) >> 6;           // uv/5 for uv<=24
        const int v = uvc - 5 * u;

        const ushort* xp = xb + (size_t)(base_hw + u * IN_HW + v) * CIN;
        bf16x8 a0 = *(const bf16x8*)xp;                                  // b=l15
        bf16x8 a1 = *(const bf16x8*)(xp + 16u * IN_HW * IN_HW * CIN);    // b+16

        float bw[8];
#pragma unroll
        for (int jj = 0; jj < 8; ++jj)      // lanes 0-15 contiguous 64B
            bw[jj] = ok ? wp[jj * 400 + cc * 32] : 0.f;
        union { bf16x8 v; unsigned u[4]; } pb;
#pragma unroll
        for (int jj = 0; jj < 4; ++jj)
            pb.u[jj] = pk2(bw[2 * jj], bw[2 * jj + 1]);

        acc0 = __builtin_amdgcn_mfma_f32_16x16x32_bf16(a0, pb.v, acc0, 0, 0, 0);
        acc1 = __builtin_amdgcn_mfma_f32_16x16x32_bf16(a1, pb.v, acc1, 0, 0, 0);
    };

    if (kh == 0) {
#pragma unroll
        for (int cc = 0; cc < 7; ++cc) step(cc, false);   // uv 0..13, clean
    } else {
#pragma unroll
        for (int cc = 7; cc < 12; ++cc) step(cc, false);  // uv 14..23, clean
        step(12, true);                                   // uv 24 + masked 25
    }

    // ---- partial D tiles -> LDS ----
    // D layout (16x16x32 bf16): col = lane&15 (=k), row = q*4 + reg (=b)
#pragma unroll
    for (int r = 0; r < 4; ++r) {
        sOut[wv][(q * 4 + r) * 16 + l15]      = acc0[r];   // b = q*4+r
        sOut[wv][(q * 4 + r + 16) * 16 + l15] = acc1[r];   // b + 16
    }
    __syncthreads();

    // ---- cross-half reduce + store: float2 per o-row, coalesced-ish ----
    const int p2 = wg * 2;
#pragma unroll
    for (int h = 0; h < 2; ++h) {
        const int o = t + h * 256;                         // o = b*16 + k
        float2 vo = { sOut[0][o] + sOut[2][o],             // pos p2
                      sOut[1][o] + sOut[3][o] };           // pos p2+1
        *(float2*)(out + (size_t)o * NPOS + p2) = vo;      // 8B aligned
    }
}

// ---- emergency fallback (ws too small): naive, correct, slow ----
__global__ __launch_bounds__(256)
void lc_naive(const float* __restrict__ x, const float* __restrict__ w,
              float* __restrict__ out) {
    const int gid = blockIdx.x * 256 + threadIdx.x;
    if (gid >= 32 * COUT * NPOS) return;
    const int j = gid % OUT_HW;
    int rest = gid / OUT_HW;
    const int i = rest % OUT_HW; rest /= OUT_HW;
    const int k = rest % COUT;
    const int b = rest / COUT;
    const float* wp = w + (size_t)(i * OUT_HW + j) * 6400 + k;
    float s = 0.f;
    for (int c = 0; c < CIN; ++c)
        for (int u = 0; u < 5; ++u)
            for (int v = 0; v < 5; ++v)
                s += x[((size_t)(b * CIN + c) * IN_HW + i + u) * IN_HW + j + v]
                   * wp[((c * 5 + u) * 5 + v) * COUT];
    out[gid] = s;
}

extern "C" void kernel_launch(void* const* d_in, const int* in_sizes, int n_in,
                              void* d_out, int out_size, void* d_ws, size_t ws_size,
                              hipStream_t stream) {
    const float* x = (const float*)d_in[0];
    const float* w = (const float*)d_in[1];
    float* out = (float*)d_out;

    const size_t xcBytes = (size_t)XC_ELE * 2;   // 4,194,304

    if (ws_size >= xcBytes) {
        ushort* xc = (ushort*)d_ws;
        make_xc<<<32 * IN_HW, 256, 0, stream>>>(x, xc);
        lc_wave<<<1800, 256, 0, stream>>>(xc, w, out);
    } else {
        lc_naive<<<(32 * COUT * NPOS + 255) / 256, 256, 0, stream>>>(x, w, out);
    }
}